// Round 1
// baseline (482.467 us; speedup 1.0000x reference)
//
#include <hip/hip_runtime.h>
#include <hip/hip_bf16.h>

// ---------------------------------------------------------------------------
// GCN: h = relu(gcnconv(x,W1,b1)); z = gcnconv(h,W2,b2); out[e]=dot(z[s],z[d])
// gcnconv: out[c] = dis[c] * ( sum_{(r,c) in E} dis[r]*xw[r] + dis[c]*xw[c] ) + b
// with deg[c] = incoming-edge count + 1 (self loop), dis = rsqrt(deg).
// Strategy: build CSR (count -> scan -> scatter) once per call, then
// aggregation is a pure gather (wave per node, lane = feature).
// ---------------------------------------------------------------------------

__global__ void deg_kernel(const int* __restrict__ col, int* __restrict__ deg, int E) {
    int e = blockIdx.x * 256 + threadIdx.x;
    if (e < E) atomicAdd(&deg[col[e]], 1);
}

__global__ void dis_kernel(const int* __restrict__ deg, float* __restrict__ dis, int n) {
    int i = blockIdx.x * 256 + threadIdx.x;
    if (i < n) dis[i] = rsqrtf((float)(deg[i] + 1));   // +1 = self loop
}

// Block-level exclusive scan: 1024 elements/block (256 thr x 4), emit block sums.
__global__ void scan1_kernel(const int* __restrict__ deg, int* __restrict__ offs,
                             int* __restrict__ bsums, int n) {
    __shared__ int sdata[256];
    const int tid = threadIdx.x;
    const int base = blockIdx.x * 1024 + tid * 4;
    int v0 = (base + 0 < n) ? deg[base + 0] : 0;
    int v1 = (base + 1 < n) ? deg[base + 1] : 0;
    int v2 = (base + 2 < n) ? deg[base + 2] : 0;
    int v3 = (base + 3 < n) ? deg[base + 3] : 0;
    int ts = v0 + v1 + v2 + v3;
    sdata[tid] = ts;
    __syncthreads();
    for (int off = 1; off < 256; off <<= 1) {
        int t = (tid >= off) ? sdata[tid - off] : 0;
        __syncthreads();
        sdata[tid] += t;
        __syncthreads();
    }
    int excl = sdata[tid] - ts;
    if (base + 0 < n) offs[base + 0] = excl;
    if (base + 1 < n) offs[base + 1] = excl + v0;
    if (base + 2 < n) offs[base + 2] = excl + v0 + v1;
    if (base + 3 < n) offs[base + 3] = excl + v0 + v1 + v2;
    if (tid == 255) bsums[blockIdx.x] = sdata[255];
}

// Single-wave exclusive scan of <=64 block sums (in place).
__global__ void scan2_kernel(int* __restrict__ bsums, int nb) {
    int lane = threadIdx.x;
    int v = (lane < nb) ? bsums[lane] : 0;
    int orig = v;
    #pragma unroll
    for (int off = 1; off < 64; off <<= 1) {
        int t = __shfl_up(v, off);
        if (lane >= off) v += t;
    }
    if (lane < nb) bsums[lane] = v - orig;   // exclusive
}

__global__ void scan3_kernel(int* __restrict__ offs, const int* __restrict__ bsums,
                             int* __restrict__ cursor, int n) {
    int i = blockIdx.x * 256 + threadIdx.x;
    if (i < n) {
        int o = offs[i] + bsums[i >> 10];
        offs[i] = o;
        cursor[i] = o;
    }
}

// csr[pos] = source node; after this, cursor[i] == end offset of node i.
__global__ void scatter_kernel(const int* __restrict__ row, const int* __restrict__ col,
                               int* __restrict__ cursor, int* __restrict__ csr, int E) {
    int e = blockIdx.x * 256 + threadIdx.x;
    if (e < E) {
        int p = atomicAdd(&cursor[col[e]], 1);
        csr[p] = row[e];
    }
}

// Y[r,c] = sum_k X[r,k] * W[k,c].  W staged in LDS (K*64 floats).
// Block = 256 thr = 4 waves; each wave computes 8 rows (64 cols across lanes).
template <int K>
__global__ __launch_bounds__(256) void gemm_kernel(const float* __restrict__ X,
                                                   const float* __restrict__ W,
                                                   float* __restrict__ Y, int nrows) {
    __shared__ float sW[K * 64];
    __shared__ float sX[4][K];
    const int tid = threadIdx.x;
    for (int i = tid * 4; i < K * 64; i += 1024)
        *(float4*)&sW[i] = *(const float4*)&W[i];
    __syncthreads();

    const int wv = tid >> 6;
    const int lane = tid & 63;
    const int base = blockIdx.x * 32 + wv * 8;
    for (int rr = 0; rr < 8; ++rr) {
        const int r = base + rr;
        if (r < nrows) {
            // stage this row of X into the wave-private LDS slice
            for (int kk = lane * 4; kk < K; kk += 256)
                *(float4*)&sX[wv][kk] = *(const float4*)&X[(long)r * K + kk];
            // same-wave DS ops complete in order; compiler inserts lgkmcnt waits
            float acc = 0.f;
            #pragma unroll
            for (int k4 = 0; k4 < K / 4; ++k4) {
                float4 xv = *(float4*)&sX[wv][k4 * 4];
                acc += xv.x * sW[(k4 * 4 + 0) * 64 + lane];
                acc += xv.y * sW[(k4 * 4 + 1) * 64 + lane];
                acc += xv.z * sW[(k4 * 4 + 2) * 64 + lane];
                acc += xv.w * sW[(k4 * 4 + 3) * 64 + lane];
            }
            Y[(long)r * 64 + lane] = acc;
        }
    }
}

// One wave per node; lane = feature. acc = dis_i*xw[i] + sum_j dis[rj]*xw[rj];
// out = acc*dis_i + b  (optionally relu'd).
template <bool RELU>
__global__ __launch_bounds__(256) void agg_kernel(const float* __restrict__ xw,
                                                  const int* __restrict__ csr,
                                                  const int* __restrict__ offs,
                                                  const int* __restrict__ ends,
                                                  const float* __restrict__ dis,
                                                  const float* __restrict__ bias,
                                                  float* __restrict__ out, int n) {
    const int wv = threadIdx.x >> 6;
    const int lane = threadIdx.x & 63;
    const int i = blockIdx.x * 4 + wv;
    if (i >= n) return;
    const float di = dis[i];
    float acc = di * xw[(long)i * 64 + lane];   // self loop (dis_i * xw_i)
    const int s = offs[i];
    const int e = ends[i];
    for (int j = s; j < e; ++j) {
        const int r = csr[j];
        acc += dis[r] * xw[(long)r * 64 + lane];
    }
    float o = acc * di + bias[lane];
    if (RELU) o = fmaxf(o, 0.f);
    out[(long)i * 64 + lane] = o;
}

// One wave per label edge: dot(z[src], z[dst]) over 64 features.
__global__ __launch_bounds__(256) void decode_kernel(const float* __restrict__ z,
                                                     const int* __restrict__ src,
                                                     const int* __restrict__ dst,
                                                     float* __restrict__ out, int L) {
    const int wv = threadIdx.x >> 6;
    const int lane = threadIdx.x & 63;
    const int e = blockIdx.x * 4 + wv;
    if (e >= L) return;
    const int s = src[e];
    const int d = dst[e];
    float p = z[(long)s * 64 + lane] * z[(long)d * 64 + lane];
    #pragma unroll
    for (int off = 32; off > 0; off >>= 1) p += __shfl_xor(p, off);
    if (lane == 0) out[e] = p;
}

extern "C" void kernel_launch(void* const* d_in, const int* in_sizes, int n_in,
                              void* d_out, int out_size, void* d_ws, size_t ws_size,
                              hipStream_t stream) {
    const float* x   = (const float*)d_in[0];
    const int*   ei  = (const int*)d_in[1];
    const int*   eli = (const int*)d_in[2];
    const float* W1  = (const float*)d_in[3];
    const float* b1  = (const float*)d_in[4];
    const float* W2  = (const float*)d_in[5];
    const float* b2  = (const float*)d_in[6];
    float* out = (float*)d_out;

    const int N = in_sizes[0] / 256;   // 50000 nodes (IN_CH = 256)
    const int E = in_sizes[1] / 2;     // 800000 edges
    const int L = in_sizes[2] / 2;     // 200000 label edges
    const int* row = ei;
    const int* col = ei + E;
    const int* src = eli;
    const int* dst = eli + L;

    char* w = (char*)d_ws;
    float* xw     = (float*)w;  w += (size_t)N * 64 * 4;   // pre-agg features (both layers)
    float* h      = (float*)w;  w += (size_t)N * 64 * 4;   // layer-1 output
    float* z      = (float*)w;  w += (size_t)N * 64 * 4;   // layer-2 output
    int*   csr    = (int*)w;    w += (size_t)E * 4;        // sources sorted by target
    int*   deg    = (int*)w;    w += (size_t)N * 4;        // incoming-edge count (no self loop)
    float* dis    = (float*)w;  w += (size_t)N * 4;        // rsqrt(deg+1)
    int*   offs   = (int*)w;    w += (size_t)N * 4;        // CSR start offsets
    int*   cursor = (int*)w;    w += (size_t)N * 4;        // scatter cursor -> CSR end offsets
    int*   bsums  = (int*)w;    w += 4096;                 // scan block sums

    hipMemsetAsync(deg, 0, (size_t)N * 4, stream);
    deg_kernel<<<(E + 255) / 256, 256, 0, stream>>>(col, deg, E);
    dis_kernel<<<(N + 255) / 256, 256, 0, stream>>>(deg, dis, N);
    const int nb = (N + 1023) / 1024;  // 49 <= 64 (single-wave scan2 limit)
    scan1_kernel<<<nb, 256, 0, stream>>>(deg, offs, bsums, N);
    scan2_kernel<<<1, 64, 0, stream>>>(bsums, nb);
    scan3_kernel<<<(N + 255) / 256, 256, 0, stream>>>(offs, bsums, cursor, N);
    scatter_kernel<<<(E + 255) / 256, 256, 0, stream>>>(row, col, cursor, csr, E);

    gemm_kernel<256><<<(N + 31) / 32, 256, 0, stream>>>(x, W1, xw, N);
    agg_kernel<true><<<(N + 3) / 4, 256, 0, stream>>>(xw, csr, offs, cursor, dis, b1, h, N);
    gemm_kernel<64><<<(N + 31) / 32, 256, 0, stream>>>(h, W2, xw, N);
    agg_kernel<false><<<(N + 3) / 4, 256, 0, stream>>>(xw, csr, offs, cursor, dis, b2, z, N);
    decode_kernel<<<(L + 3) / 4, 256, 0, stream>>>(z, src, dst, out, L);
}

// Round 2
// 429.595 us; speedup vs baseline: 1.1231x; 1.1231x over previous
//
#include <hip/hip_runtime.h>
#include <hip/hip_bf16.h>

// ---------------------------------------------------------------------------
// GCN: h = relu(gcnconv(x,W1,b1)); z = gcnconv(h,W2,b2); out[e]=dot(z[s],z[d])
// CSR build (count->scan->scatter) once per call; aggregation = pure gather.
// GEMM: 64x64 tile/block, thread=(row lane, 16-col group), 16 FMA per LDS read.
// ---------------------------------------------------------------------------

__global__ void deg_kernel(const int* __restrict__ col, int* __restrict__ deg, int E) {
    int e = blockIdx.x * 256 + threadIdx.x;
    if (e < E) atomicAdd(&deg[col[e]], 1);
}

__global__ void dis_kernel(const int* __restrict__ deg, float* __restrict__ dis, int n) {
    int i = blockIdx.x * 256 + threadIdx.x;
    if (i < n) dis[i] = rsqrtf((float)(deg[i] + 1));   // +1 = self loop
}

// Block-level exclusive scan: 1024 elements/block (256 thr x 4), emit block sums.
__global__ void scan1_kernel(const int* __restrict__ deg, int* __restrict__ offs,
                             int* __restrict__ bsums, int n) {
    __shared__ int sdata[256];
    const int tid = threadIdx.x;
    const int base = blockIdx.x * 1024 + tid * 4;
    int v0 = (base + 0 < n) ? deg[base + 0] : 0;
    int v1 = (base + 1 < n) ? deg[base + 1] : 0;
    int v2 = (base + 2 < n) ? deg[base + 2] : 0;
    int v3 = (base + 3 < n) ? deg[base + 3] : 0;
    int ts = v0 + v1 + v2 + v3;
    sdata[tid] = ts;
    __syncthreads();
    for (int off = 1; off < 256; off <<= 1) {
        int t = (tid >= off) ? sdata[tid - off] : 0;
        __syncthreads();
        sdata[tid] += t;
        __syncthreads();
    }
    int excl = sdata[tid] - ts;
    if (base + 0 < n) offs[base + 0] = excl;
    if (base + 1 < n) offs[base + 1] = excl + v0;
    if (base + 2 < n) offs[base + 2] = excl + v0 + v1;
    if (base + 3 < n) offs[base + 3] = excl + v0 + v1 + v2;
    if (tid == 255) bsums[blockIdx.x] = sdata[255];
}

// Single-wave exclusive scan of <=64 block sums (in place).
__global__ void scan2_kernel(int* __restrict__ bsums, int nb) {
    int lane = threadIdx.x;
    int v = (lane < nb) ? bsums[lane] : 0;
    int orig = v;
    #pragma unroll
    for (int off = 1; off < 64; off <<= 1) {
        int t = __shfl_up(v, off);
        if (lane >= off) v += t;
    }
    if (lane < nb) bsums[lane] = v - orig;   // exclusive
}

__global__ void scan3_kernel(int* __restrict__ offs, const int* __restrict__ bsums,
                             int* __restrict__ cursor, int n) {
    int i = blockIdx.x * 256 + threadIdx.x;
    if (i < n) {
        int o = offs[i] + bsums[i >> 10];
        offs[i] = o;
        cursor[i] = o;
    }
}

// csr[pos] = source node; after this, cursor[i] == end offset of node i.
__global__ void scatter_kernel(const int* __restrict__ row, const int* __restrict__ col,
                               int* __restrict__ cursor, int* __restrict__ csr, int E) {
    int e = blockIdx.x * 256 + threadIdx.x;
    if (e < E) {
        int p = atomicAdd(&cursor[col[e]], 1);
        csr[p] = row[e];
    }
}

// Y[N,64] = X[N,K] @ W[K,64].  Block = 256 thr covers 64 rows x 64 cols.
// r = tid&63 (row lane), g = tid>>6 (col group: cols g*16..g*16+15).
// X chunk (64 rows x 64 k) staged in LDS with pad-65 (banks (r+k)%32 -> 2-way, free).
// Per k: 1 ds_read_b32 + 4 wave-uniform W float4 loads + 16 FMAs.
template <int K>
__global__ __launch_bounds__(256) void gemm_tile(const float* __restrict__ X,
                                                 const float* __restrict__ W,
                                                 float* __restrict__ Y, int nrows) {
    __shared__ float sX[64 * 65];
    const int tid = threadIdx.x;
    const int r = tid & 63;
    const int g = tid >> 6;
    const int rowbase = blockIdx.x * 64;

    float acc[16];
    #pragma unroll
    for (int i = 0; i < 16; ++i) acc[i] = 0.f;

    const int lr = tid >> 2;            // load row (0..63)
    const int lc = tid & 3;             // load quarter within 16 float4s
    int grow = rowbase + lr;
    if (grow >= nrows) grow = nrows - 1;     // clamp; result discarded on store
    const float* xrow = X + (long)grow * K;

    for (int kc = 0; kc < K; kc += 64) {
        __syncthreads();
        #pragma unroll
        for (int t = 0; t < 4; ++t) {
            const int k4 = lc + t * 4;       // float4 index within the 16 of this chunk
            float4 v = *(const float4*)&xrow[kc + k4 * 4];
            const int b = lr * 65 + k4 * 4;
            sX[b + 0] = v.x; sX[b + 1] = v.y; sX[b + 2] = v.z; sX[b + 3] = v.w;
        }
        __syncthreads();
        const float* Wk = W + (long)kc * 64 + g * 16;
        #pragma unroll 4
        for (int k = 0; k < 64; ++k) {
            const float xv = sX[r * 65 + k];
            const float4 w0 = *(const float4*)&Wk[(long)k * 64 + 0];
            const float4 w1 = *(const float4*)&Wk[(long)k * 64 + 4];
            const float4 w2 = *(const float4*)&Wk[(long)k * 64 + 8];
            const float4 w3 = *(const float4*)&Wk[(long)k * 64 + 12];
            acc[0]  = fmaf(xv, w0.x, acc[0]);  acc[1]  = fmaf(xv, w0.y, acc[1]);
            acc[2]  = fmaf(xv, w0.z, acc[2]);  acc[3]  = fmaf(xv, w0.w, acc[3]);
            acc[4]  = fmaf(xv, w1.x, acc[4]);  acc[5]  = fmaf(xv, w1.y, acc[5]);
            acc[6]  = fmaf(xv, w1.z, acc[6]);  acc[7]  = fmaf(xv, w1.w, acc[7]);
            acc[8]  = fmaf(xv, w2.x, acc[8]);  acc[9]  = fmaf(xv, w2.y, acc[9]);
            acc[10] = fmaf(xv, w2.z, acc[10]); acc[11] = fmaf(xv, w2.w, acc[11]);
            acc[12] = fmaf(xv, w3.x, acc[12]); acc[13] = fmaf(xv, w3.y, acc[13]);
            acc[14] = fmaf(xv, w3.z, acc[14]); acc[15] = fmaf(xv, w3.w, acc[15]);
        }
    }

    const int orow = rowbase + r;
    if (orow < nrows) {
        float* yp = Y + (long)orow * 64 + g * 16;
        *(float4*)&yp[0]  = make_float4(acc[0],  acc[1],  acc[2],  acc[3]);
        *(float4*)&yp[4]  = make_float4(acc[4],  acc[5],  acc[6],  acc[7]);
        *(float4*)&yp[8]  = make_float4(acc[8],  acc[9],  acc[10], acc[11]);
        *(float4*)&yp[12] = make_float4(acc[12], acc[13], acc[14], acc[15]);
    }
}

// One wave per node, split into 4 groups of 16 lanes; each group gathers a
// different neighbor row (float4 per lane) -> 4 independent loads in flight.
// Cross-group xor-shuffle reduce at the end.
template <bool RELU>
__global__ __launch_bounds__(256) void agg_kernel(const float* __restrict__ xw,
                                                  const int* __restrict__ csr,
                                                  const int* __restrict__ offs,
                                                  const int* __restrict__ ends,
                                                  const float* __restrict__ dis,
                                                  const float* __restrict__ bias,
                                                  float* __restrict__ out, int n) {
    const int wv = threadIdx.x >> 6;
    const int lane = threadIdx.x & 63;
    const int grp = lane >> 4;
    const int fl = lane & 15;
    const int i = blockIdx.x * 4 + wv;
    if (i >= n) return;
    const float di = dis[i];
    float4 acc = make_float4(0.f, 0.f, 0.f, 0.f);
    if (grp == 0) {   // self loop counted once
        const float4 v = *(const float4*)&xw[(long)i * 64 + fl * 4];
        acc.x = di * v.x; acc.y = di * v.y; acc.z = di * v.z; acc.w = di * v.w;
    }
    const int s = offs[i];
    const int e = ends[i];
    for (int j = s + grp; j < e; j += 4) {
        const int rs = csr[j];
        const float w = dis[rs];
        const float4 v = *(const float4*)&xw[(long)rs * 64 + fl * 4];
        acc.x = fmaf(w, v.x, acc.x); acc.y = fmaf(w, v.y, acc.y);
        acc.z = fmaf(w, v.z, acc.z); acc.w = fmaf(w, v.w, acc.w);
    }
    acc.x += __shfl_xor(acc.x, 16); acc.y += __shfl_xor(acc.y, 16);
    acc.z += __shfl_xor(acc.z, 16); acc.w += __shfl_xor(acc.w, 16);
    acc.x += __shfl_xor(acc.x, 32); acc.y += __shfl_xor(acc.y, 32);
    acc.z += __shfl_xor(acc.z, 32); acc.w += __shfl_xor(acc.w, 32);
    if (grp == 0) {
        const float4 b = *(const float4*)&bias[fl * 4];
        float4 o;
        o.x = fmaf(acc.x, di, b.x); o.y = fmaf(acc.y, di, b.y);
        o.z = fmaf(acc.z, di, b.z); o.w = fmaf(acc.w, di, b.w);
        if (RELU) {
            o.x = fmaxf(o.x, 0.f); o.y = fmaxf(o.y, 0.f);
            o.z = fmaxf(o.z, 0.f); o.w = fmaxf(o.w, 0.f);
        }
        *(float4*)&out[(long)i * 64 + fl * 4] = o;
    }
}

// 16 lanes per label edge: float4 gathers of z[src], z[dst]; 4-step xor reduce.
__global__ __launch_bounds__(256) void decode_kernel(const float* __restrict__ z,
                                                     const int* __restrict__ src,
                                                     const int* __restrict__ dst,
                                                     float* __restrict__ out, int L) {
    const int t = blockIdx.x * 256 + threadIdx.x;
    const int e = t >> 4;
    const int fl = t & 15;
    if (e >= L) return;
    const int s = src[e];
    const int d = dst[e];
    const float4 a = *(const float4*)&z[(long)s * 64 + fl * 4];
    const float4 b = *(const float4*)&z[(long)d * 64 + fl * 4];
    float p = a.x * b.x + a.y * b.y + a.z * b.z + a.w * b.w;
    p += __shfl_xor(p, 8); p += __shfl_xor(p, 4);
    p += __shfl_xor(p, 2); p += __shfl_xor(p, 1);
    if (fl == 0) out[e] = p;
}

extern "C" void kernel_launch(void* const* d_in, const int* in_sizes, int n_in,
                              void* d_out, int out_size, void* d_ws, size_t ws_size,
                              hipStream_t stream) {
    const float* x   = (const float*)d_in[0];
    const int*   ei  = (const int*)d_in[1];
    const int*   eli = (const int*)d_in[2];
    const float* W1  = (const float*)d_in[3];
    const float* b1  = (const float*)d_in[4];
    const float* W2  = (const float*)d_in[5];
    const float* b2  = (const float*)d_in[6];
    float* out = (float*)d_out;

    const int N = in_sizes[0] / 256;   // 50000 nodes (IN_CH = 256)
    const int E = in_sizes[1] / 2;     // 800000 edges
    const int L = in_sizes[2] / 2;     // 200000 label edges
    const int* row = ei;
    const int* col = ei + E;
    const int* src = eli;
    const int* dst = eli + L;

    char* w = (char*)d_ws;
    float* xw     = (float*)w;  w += (size_t)N * 64 * 4;   // pre-agg features (both layers)
    float* h      = (float*)w;  w += (size_t)N * 64 * 4;   // layer-1 output
    float* z      = (float*)w;  w += (size_t)N * 64 * 4;   // layer-2 output
    int*   csr    = (int*)w;    w += (size_t)E * 4;        // sources sorted by target
    int*   deg    = (int*)w;    w += (size_t)N * 4;        // incoming-edge count (no self loop)
    float* dis    = (float*)w;  w += (size_t)N * 4;        // rsqrt(deg+1)
    int*   offs   = (int*)w;    w += (size_t)N * 4;        // CSR start offsets
    int*   cursor = (int*)w;    w += (size_t)N * 4;        // scatter cursor -> CSR end offsets
    int*   bsums  = (int*)w;    w += 4096;                 // scan block sums

    hipMemsetAsync(deg, 0, (size_t)N * 4, stream);
    deg_kernel<<<(E + 255) / 256, 256, 0, stream>>>(col, deg, E);
    dis_kernel<<<(N + 255) / 256, 256, 0, stream>>>(deg, dis, N);
    const int nb = (N + 1023) / 1024;  // 49 <= 64 (single-wave scan2 limit)
    scan1_kernel<<<nb, 256, 0, stream>>>(deg, offs, bsums, N);
    scan2_kernel<<<1, 64, 0, stream>>>(bsums, nb);
    scan3_kernel<<<(N + 255) / 256, 256, 0, stream>>>(offs, bsums, cursor, N);
    scatter_kernel<<<(E + 255) / 256, 256, 0, stream>>>(row, col, cursor, csr, E);

    gemm_tile<256><<<(N + 63) / 64, 256, 0, stream>>>(x, W1, xw, N);
    agg_kernel<true><<<(N + 3) / 4, 256, 0, stream>>>(xw, csr, offs, cursor, dis, b1, h, N);
    gemm_tile<64><<<(N + 63) / 64, 256, 0, stream>>>(h, W2, xw, N);
    agg_kernel<false><<<(N + 3) / 4, 256, 0, stream>>>(xw, csr, offs, cursor, dis, b2, z, N);
    decode_kernel<<<(L + 15) / 16, 256, 0, stream>>>(z, src, dst, out, L);
}

// Round 3
// 308.851 us; speedup vs baseline: 1.5621x; 1.3909x over previous
//
#include <hip/hip_runtime.h>
#include <hip/hip_bf16.h>

// ---------------------------------------------------------------------------
// GCN: h = relu(gcnconv(x,W1,b1)); z = gcnconv(h,W2,b2); out[e]=dot(z[s],z[d])
// CSR build (count->scan->scatter) once per call; aggregation = pure gather.
// GEMM: 64x64 block tile, 4x4 register micro-tile, both operands in LDS
// (k-major), 16 FMA per 2 ds_read_b128, zero global loads in the k-loop.
// ---------------------------------------------------------------------------

__global__ void deg_kernel(const int* __restrict__ col, int* __restrict__ deg, int E) {
    int e = blockIdx.x * 256 + threadIdx.x;
    if (e < E) atomicAdd(&deg[col[e]], 1);
}

__global__ void dis_kernel(const int* __restrict__ deg, float* __restrict__ dis, int n) {
    int i = blockIdx.x * 256 + threadIdx.x;
    if (i < n) dis[i] = rsqrtf((float)(deg[i] + 1));   // +1 = self loop
}

// Block-level exclusive scan: 1024 elements/block (256 thr x 4), emit block sums.
__global__ void scan1_kernel(const int* __restrict__ deg, int* __restrict__ offs,
                             int* __restrict__ bsums, int n) {
    __shared__ int sdata[256];
    const int tid = threadIdx.x;
    const int base = blockIdx.x * 1024 + tid * 4;
    int v0 = (base + 0 < n) ? deg[base + 0] : 0;
    int v1 = (base + 1 < n) ? deg[base + 1] : 0;
    int v2 = (base + 2 < n) ? deg[base + 2] : 0;
    int v3 = (base + 3 < n) ? deg[base + 3] : 0;
    int ts = v0 + v1 + v2 + v3;
    sdata[tid] = ts;
    __syncthreads();
    for (int off = 1; off < 256; off <<= 1) {
        int t = (tid >= off) ? sdata[tid - off] : 0;
        __syncthreads();
        sdata[tid] += t;
        __syncthreads();
    }
    int excl = sdata[tid] - ts;
    if (base + 0 < n) offs[base + 0] = excl;
    if (base + 1 < n) offs[base + 1] = excl + v0;
    if (base + 2 < n) offs[base + 2] = excl + v0 + v1;
    if (base + 3 < n) offs[base + 3] = excl + v0 + v1 + v2;
    if (tid == 255) bsums[blockIdx.x] = sdata[255];
}

// Single-wave exclusive scan of <=64 block sums (in place).
__global__ void scan2_kernel(int* __restrict__ bsums, int nb) {
    int lane = threadIdx.x;
    int v = (lane < nb) ? bsums[lane] : 0;
    int orig = v;
    #pragma unroll
    for (int off = 1; off < 64; off <<= 1) {
        int t = __shfl_up(v, off);
        if (lane >= off) v += t;
    }
    if (lane < nb) bsums[lane] = v - orig;   // exclusive
}

__global__ void scan3_kernel(int* __restrict__ offs, const int* __restrict__ bsums,
                             int* __restrict__ cursor, int n) {
    int i = blockIdx.x * 256 + threadIdx.x;
    if (i < n) {
        int o = offs[i] + bsums[i >> 10];
        offs[i] = o;
        cursor[i] = o;
    }
}

// csr[pos] = source node; after this, cursor[i] == end offset of node i.
__global__ void scatter_kernel(const int* __restrict__ row, const int* __restrict__ col,
                               int* __restrict__ cursor, int* __restrict__ csr, int E) {
    int e = blockIdx.x * 256 + threadIdx.x;
    if (e < E) {
        int p = atomicAdd(&cursor[col[e]], 1);
        csr[p] = row[e];
    }
}

// Y[N,64] = X[N,K] @ W[K,64].
// Block = 256 thr = 16x16 thread grid; thread (ty,tx) computes rows ty*4..+3,
// cols tx*4..+3 (4x4 in registers). LDS holds the 64-row x 64-k X chunk
// TRANSPOSED (k-major, sX[k*64+r]) and the 64-k x 64-col W chunk (natural
// k-major, sW[k*64+c]) so both fragments are single ds_read_b128 per k.
// x-frag: 4 distinct addrs/wave (broadcast); w-frag: 16 distinct, 2-way (free).
template <int K>
__global__ __launch_bounds__(256) void gemm_tile(const float* __restrict__ X,
                                                 const float* __restrict__ W,
                                                 float* __restrict__ Y, int nrows) {
    __shared__ float sX[64 * 64];
    __shared__ float sW[64 * 64];
    const int tid = threadIdx.x;
    const int tx = tid & 15;         // col group
    const int ty = tid >> 4;         // row group
    const int rowbase = blockIdx.x * 64;

    float acc[16];
    #pragma unroll
    for (int i = 0; i < 16; ++i) acc[i] = 0.f;

    const int lr = tid & 63;         // loader row (0..63)
    const int lq = tid >> 6;         // loader k-quarter (16 k's each)
    int grow = rowbase + lr;
    if (grow >= nrows) grow = nrows - 1;   // clamp; stores are guarded
    const float* xrow = X + (long)grow * K;

    for (int kc = 0; kc < K; kc += 64) {
        if (kc) __syncthreads();     // protect LDS before overwrite
        // stage W chunk (straight copy, 16 floats/thread, coalesced)
        #pragma unroll
        for (int i = 0; i < 4; ++i) {
            const int o = tid * 4 + i * 1024;
            *(float4*)&sW[o] = *(const float4*)&W[(long)kc * 64 + o];
        }
        // stage X chunk transposed (scalar LDS writes, consecutive r = free)
        #pragma unroll
        for (int t = 0; t < 4; ++t) {
            const int k = lq * 16 + t * 4;
            const float4 v = *(const float4*)&xrow[kc + k];
            sX[(k + 0) * 64 + lr] = v.x;
            sX[(k + 1) * 64 + lr] = v.y;
            sX[(k + 2) * 64 + lr] = v.z;
            sX[(k + 3) * 64 + lr] = v.w;
        }
        __syncthreads();
        #pragma unroll 4
        for (int k = 0; k < 64; ++k) {
            const float4 xv = *(const float4*)&sX[k * 64 + ty * 4];
            const float4 wv = *(const float4*)&sW[k * 64 + tx * 4];
            acc[0]  = fmaf(xv.x, wv.x, acc[0]);
            acc[1]  = fmaf(xv.x, wv.y, acc[1]);
            acc[2]  = fmaf(xv.x, wv.z, acc[2]);
            acc[3]  = fmaf(xv.x, wv.w, acc[3]);
            acc[4]  = fmaf(xv.y, wv.x, acc[4]);
            acc[5]  = fmaf(xv.y, wv.y, acc[5]);
            acc[6]  = fmaf(xv.y, wv.z, acc[6]);
            acc[7]  = fmaf(xv.y, wv.w, acc[7]);
            acc[8]  = fmaf(xv.z, wv.x, acc[8]);
            acc[9]  = fmaf(xv.z, wv.y, acc[9]);
            acc[10] = fmaf(xv.z, wv.z, acc[10]);
            acc[11] = fmaf(xv.z, wv.w, acc[11]);
            acc[12] = fmaf(xv.w, wv.x, acc[12]);
            acc[13] = fmaf(xv.w, wv.y, acc[13]);
            acc[14] = fmaf(xv.w, wv.z, acc[14]);
            acc[15] = fmaf(xv.w, wv.w, acc[15]);
        }
    }

    #pragma unroll
    for (int i = 0; i < 4; ++i) {
        const int orow = rowbase + ty * 4 + i;
        if (orow < nrows) {
            *(float4*)&Y[(long)orow * 64 + tx * 4] =
                make_float4(acc[i * 4 + 0], acc[i * 4 + 1], acc[i * 4 + 2], acc[i * 4 + 3]);
        }
    }
}

// One wave per node, split into 4 groups of 16 lanes; each group gathers a
// different neighbor row (float4 per lane) -> 4 independent loads in flight.
// Cross-group xor-shuffle reduce at the end.
template <bool RELU>
__global__ __launch_bounds__(256) void agg_kernel(const float* __restrict__ xw,
                                                  const int* __restrict__ csr,
                                                  const int* __restrict__ offs,
                                                  const int* __restrict__ ends,
                                                  const float* __restrict__ dis,
                                                  const float* __restrict__ bias,
                                                  float* __restrict__ out, int n) {
    const int wv = threadIdx.x >> 6;
    const int lane = threadIdx.x & 63;
    const int grp = lane >> 4;
    const int fl = lane & 15;
    const int i = blockIdx.x * 4 + wv;
    if (i >= n) return;
    const float di = dis[i];
    float4 acc = make_float4(0.f, 0.f, 0.f, 0.f);
    if (grp == 0) {   // self loop counted once
        const float4 v = *(const float4*)&xw[(long)i * 64 + fl * 4];
        acc.x = di * v.x; acc.y = di * v.y; acc.z = di * v.z; acc.w = di * v.w;
    }
    const int s = offs[i];
    const int e = ends[i];
    for (int j = s + grp; j < e; j += 4) {
        const int rs = csr[j];
        const float w = dis[rs];
        const float4 v = *(const float4*)&xw[(long)rs * 64 + fl * 4];
        acc.x = fmaf(w, v.x, acc.x); acc.y = fmaf(w, v.y, acc.y);
        acc.z = fmaf(w, v.z, acc.z); acc.w = fmaf(w, v.w, acc.w);
    }
    acc.x += __shfl_xor(acc.x, 16); acc.y += __shfl_xor(acc.y, 16);
    acc.z += __shfl_xor(acc.z, 16); acc.w += __shfl_xor(acc.w, 16);
    acc.x += __shfl_xor(acc.x, 32); acc.y += __shfl_xor(acc.y, 32);
    acc.z += __shfl_xor(acc.z, 32); acc.w += __shfl_xor(acc.w, 32);
    if (grp == 0) {
        const float4 b = *(const float4*)&bias[fl * 4];
        float4 o;
        o.x = fmaf(acc.x, di, b.x); o.y = fmaf(acc.y, di, b.y);
        o.z = fmaf(acc.z, di, b.z); o.w = fmaf(acc.w, di, b.w);
        if (RELU) {
            o.x = fmaxf(o.x, 0.f); o.y = fmaxf(o.y, 0.f);
            o.z = fmaxf(o.z, 0.f); o.w = fmaxf(o.w, 0.f);
        }
        *(float4*)&out[(long)i * 64 + fl * 4] = o;
    }
}

// 16 lanes per label edge: float4 gathers of z[src], z[dst]; 4-step xor reduce.
__global__ __launch_bounds__(256) void decode_kernel(const float* __restrict__ z,
                                                     const int* __restrict__ src,
                                                     const int* __restrict__ dst,
                                                     float* __restrict__ out, int L) {
    const int t = blockIdx.x * 256 + threadIdx.x;
    const int e = t >> 4;
    const int fl = t & 15;
    if (e >= L) return;
    const int s = src[e];
    const int d = dst[e];
    const float4 a = *(const float4*)&z[(long)s * 64 + fl * 4];
    const float4 b = *(const float4*)&z[(long)d * 64 + fl * 4];
    float p = a.x * b.x + a.y * b.y + a.z * b.z + a.w * b.w;
    p += __shfl_xor(p, 8); p += __shfl_xor(p, 4);
    p += __shfl_xor(p, 2); p += __shfl_xor(p, 1);
    if (fl == 0) out[e] = p;
}

extern "C" void kernel_launch(void* const* d_in, const int* in_sizes, int n_in,
                              void* d_out, int out_size, void* d_ws, size_t ws_size,
                              hipStream_t stream) {
    const float* x   = (const float*)d_in[0];
    const int*   ei  = (const int*)d_in[1];
    const int*   eli = (const int*)d_in[2];
    const float* W1  = (const float*)d_in[3];
    const float* b1  = (const float*)d_in[4];
    const float* W2  = (const float*)d_in[5];
    const float* b2  = (const float*)d_in[6];
    float* out = (float*)d_out;

    const int N = in_sizes[0] / 256;   // 50000 nodes (IN_CH = 256)
    const int E = in_sizes[1] / 2;     // 800000 edges
    const int L = in_sizes[2] / 2;     // 200000 label edges
    const int* row = ei;
    const int* col = ei + E;
    const int* src = eli;
    const int* dst = eli + L;

    char* w = (char*)d_ws;
    float* xw     = (float*)w;  w += (size_t)N * 64 * 4;   // pre-agg features (both layers)
    float* h      = (float*)w;  w += (size_t)N * 64 * 4;   // layer-1 output
    float* z      = (float*)w;  w += (size_t)N * 64 * 4;   // layer-2 output
    int*   csr    = (int*)w;    w += (size_t)E * 4;        // sources sorted by target
    int*   deg    = (int*)w;    w += (size_t)N * 4;        // incoming-edge count (no self loop)
    float* dis    = (float*)w;  w += (size_t)N * 4;        // rsqrt(deg+1)
    int*   offs   = (int*)w;    w += (size_t)N * 4;        // CSR start offsets
    int*   cursor = (int*)w;    w += (size_t)N * 4;        // scatter cursor -> CSR end offsets
    int*   bsums  = (int*)w;    w += 4096;                 // scan block sums

    hipMemsetAsync(deg, 0, (size_t)N * 4, stream);
    deg_kernel<<<(E + 255) / 256, 256, 0, stream>>>(col, deg, E);
    dis_kernel<<<(N + 255) / 256, 256, 0, stream>>>(deg, dis, N);
    const int nb = (N + 1023) / 1024;  // 49 <= 64 (single-wave scan2 limit)
    scan1_kernel<<<nb, 256, 0, stream>>>(deg, offs, bsums, N);
    scan2_kernel<<<1, 64, 0, stream>>>(bsums, nb);
    scan3_kernel<<<(N + 255) / 256, 256, 0, stream>>>(offs, bsums, cursor, N);
    scatter_kernel<<<(E + 255) / 256, 256, 0, stream>>>(row, col, cursor, csr, E);

    gemm_tile<256><<<(N + 63) / 64, 256, 0, stream>>>(x, W1, xw, N);
    agg_kernel<true><<<(N + 3) / 4, 256, 0, stream>>>(xw, csr, offs, cursor, dis, b1, h, N);
    gemm_tile<64><<<(N + 63) / 64, 256, 0, stream>>>(h, W2, xw, N);
    agg_kernel<false><<<(N + 3) / 4, 256, 0, stream>>>(xw, csr, offs, cursor, dis, b2, z, N);
    decode_kernel<<<(L + 15) / 16, 256, 0, stream>>>(z, src, dst, out, L);
}

// Round 4
// 266.508 us; speedup vs baseline: 1.8103x; 1.1589x over previous
//
#include <hip/hip_runtime.h>
#include <hip/hip_bf16.h>

// ---------------------------------------------------------------------------
// GCN: h = relu(gcnconv(x,W1,b1)); z = gcnconv(h,W2,b2); out[e]=dot(z[s],z[d])
// CSR build = bucketed counting sort (hist -> scan -> reorder -> bucket_csr):
// all random writes land in single-block-owned windows (full-line writebacks),
// replacing the global atomic scatter that caused 52MB of partial-line HBM
// write traffic. Aggregation = pure gather over CSR.
// GEMM: 64x64 block tile, 4x4 register micro-tile, both operands in LDS.
// ---------------------------------------------------------------------------

constexpr int NC = 256;      // edge chunks (= hist/reorder grid)
constexpr int NBPAD = 256;   // padded bucket count (>= nbk, = block size)
constexpr int BSHIFT = 8;    // 256 nodes per bucket

__global__ __launch_bounds__(256) void hist_kernel(const int* __restrict__ col,
                                                   int* __restrict__ hist, int E, int CE) {
    __shared__ int hl[NBPAD];
    const int t = threadIdx.x, c = blockIdx.x;
    hl[t] = 0;
    __syncthreads();
    const int s = c * CE, e = min(E, s + CE);
    for (int i = s + t; i < e; i += 256) atomicAdd(&hl[col[i] >> BSHIFT], 1);
    __syncthreads();
    hist[t * NC + c] = hl[t];   // bucket-major for the linear scan
}

// Exclusive scan of the 65536-entry histogram (single block, 256 per thread).
__global__ __launch_bounds__(256) void scan_hist_kernel(int* __restrict__ hist) {
    __shared__ int sums[256];
    const int t = threadIdx.x;
    const int base = t * 256;
    int s = 0;
    for (int i = 0; i < 256; ++i) s += hist[base + i];
    sums[t] = s;
    __syncthreads();
    for (int off = 1; off < 256; off <<= 1) {
        int u = (t >= off) ? sums[t - off] : 0;
        __syncthreads();
        sums[t] += u;
        __syncthreads();
    }
    int run = sums[t] - s;   // exclusive block prefix
    for (int i = 0; i < 256; ++i) {
        int x = hist[base + i];
        hist[base + i] = run;
        run += x;
    }
}

// Scatter (row,col) pairs into per-(bucket,chunk) contiguous runs of part[].
__global__ __launch_bounds__(256) void reorder_kernel(const int* __restrict__ row,
                                                      const int* __restrict__ col,
                                                      const int* __restrict__ hist,
                                                      int2* __restrict__ part, int E, int CE) {
    __shared__ int cur[NBPAD];
    const int t = threadIdx.x, c = blockIdx.x;
    cur[t] = hist[t * NC + c];
    __syncthreads();
    const int s = c * CE, e = min(E, s + CE);
    for (int i = s + t; i < e; i += 256) {
        const int r = row[i], cl = col[i];
        const int p = atomicAdd(&cur[cl >> BSHIFT], 1);
        part[p] = make_int2(r, cl);
    }
}

// One block per bucket: LDS degree count -> LDS scan -> offs/dis -> scatter
// rows into the bucket's private csr window (stays in one XCD's L2).
__global__ __launch_bounds__(256) void bucket_csr_kernel(const int2* __restrict__ part,
                                                         const int* __restrict__ hist,
                                                         int* __restrict__ csr,
                                                         int* __restrict__ offs,
                                                         float* __restrict__ dis,
                                                         int N, int E, int nbk) {
    __shared__ int cnt[256];
    __shared__ int sc[256];
    const int t = threadIdx.x, b = blockIdx.x;
    const int base = b << BSHIFT;
    const int bstart = hist[b * NC];
    const int bend = (b + 1 < NBPAD) ? hist[(b + 1) * NC] : E;
    const int m = bend - bstart;
    cnt[t] = 0;
    __syncthreads();
    for (int i = t; i < m; i += 256) atomicAdd(&cnt[part[bstart + i].y - base], 1);
    __syncthreads();
    const int v = cnt[t];
    sc[t] = v;
    __syncthreads();
    for (int off = 1; off < 256; off <<= 1) {
        int u = (t >= off) ? sc[t - off] : 0;
        __syncthreads();
        sc[t] += u;
        __syncthreads();
    }
    const int excl = sc[t] - v;
    const int node = base + t;
    if (node < N) {
        offs[node] = bstart + excl;
        dis[node] = rsqrtf((float)(v + 1));   // +1 = self loop
    }
    sc[t] = excl;          // repurpose as scatter cursor
    __syncthreads();
    for (int i = t; i < m; i += 256) {
        const int2 ec = part[bstart + i];
        const int p = atomicAdd(&sc[ec.y - base], 1);
        csr[bstart + p] = ec.x;
    }
    if (b == nbk - 1 && t == 0) offs[N] = E;
}

// Y[N,64] = X[N,K] @ W[K,64].
// Block = 256 thr = 16x16 thread grid; thread (ty,tx) computes a 4x4 micro-
// tile. LDS: X chunk transposed (k-major sX[k*64+r]) and W chunk (sW[k*64+c]);
// per k: 2 ds_read_b128 + 16 FMAs, zero global loads in the k-loop.
template <int K>
__global__ __launch_bounds__(256) void gemm_tile(const float* __restrict__ X,
                                                 const float* __restrict__ W,
                                                 float* __restrict__ Y, int nrows) {
    __shared__ float sX[64 * 64];
    __shared__ float sW[64 * 64];
    const int tid = threadIdx.x;
    const int tx = tid & 15;         // col group
    const int ty = tid >> 4;         // row group
    const int rowbase = blockIdx.x * 64;

    float acc[16];
    #pragma unroll
    for (int i = 0; i < 16; ++i) acc[i] = 0.f;

    const int lr = tid & 63;         // loader row (0..63)
    const int lq = tid >> 6;         // loader k-quarter (16 k's each)
    int grow = rowbase + lr;
    if (grow >= nrows) grow = nrows - 1;   // clamp; stores are guarded
    const float* xrow = X + (long)grow * K;

    for (int kc = 0; kc < K; kc += 64) {
        if (kc) __syncthreads();     // protect LDS before overwrite
        #pragma unroll
        for (int i = 0; i < 4; ++i) {
            const int o = tid * 4 + i * 1024;
            *(float4*)&sW[o] = *(const float4*)&W[(long)kc * 64 + o];
        }
        #pragma unroll
        for (int t = 0; t < 4; ++t) {
            const int k = lq * 16 + t * 4;
            const float4 v = *(const float4*)&xrow[kc + k];
            sX[(k + 0) * 64 + lr] = v.x;
            sX[(k + 1) * 64 + lr] = v.y;
            sX[(k + 2) * 64 + lr] = v.z;
            sX[(k + 3) * 64 + lr] = v.w;
        }
        __syncthreads();
        #pragma unroll 4
        for (int k = 0; k < 64; ++k) {
            const float4 xv = *(const float4*)&sX[k * 64 + ty * 4];
            const float4 wv = *(const float4*)&sW[k * 64 + tx * 4];
            acc[0]  = fmaf(xv.x, wv.x, acc[0]);
            acc[1]  = fmaf(xv.x, wv.y, acc[1]);
            acc[2]  = fmaf(xv.x, wv.z, acc[2]);
            acc[3]  = fmaf(xv.x, wv.w, acc[3]);
            acc[4]  = fmaf(xv.y, wv.x, acc[4]);
            acc[5]  = fmaf(xv.y, wv.y, acc[5]);
            acc[6]  = fmaf(xv.y, wv.z, acc[6]);
            acc[7]  = fmaf(xv.y, wv.w, acc[7]);
            acc[8]  = fmaf(xv.z, wv.x, acc[8]);
            acc[9]  = fmaf(xv.z, wv.y, acc[9]);
            acc[10] = fmaf(xv.z, wv.z, acc[10]);
            acc[11] = fmaf(xv.z, wv.w, acc[11]);
            acc[12] = fmaf(xv.w, wv.x, acc[12]);
            acc[13] = fmaf(xv.w, wv.y, acc[13]);
            acc[14] = fmaf(xv.w, wv.z, acc[14]);
            acc[15] = fmaf(xv.w, wv.w, acc[15]);
        }
    }

    #pragma unroll
    for (int i = 0; i < 4; ++i) {
        const int orow = rowbase + ty * 4 + i;
        if (orow < nrows) {
            *(float4*)&Y[(long)orow * 64 + tx * 4] =
                make_float4(acc[i * 4 + 0], acc[i * 4 + 1], acc[i * 4 + 2], acc[i * 4 + 3]);
        }
    }
}

// One wave per node, 4 groups of 16 lanes; each group gathers a different
// neighbor row (float4/lane) -> 4 independent loads in flight; xor reduce.
template <bool RELU>
__global__ __launch_bounds__(256) void agg_kernel(const float* __restrict__ xw,
                                                  const int* __restrict__ csr,
                                                  const int* __restrict__ offs,
                                                  const float* __restrict__ dis,
                                                  const float* __restrict__ bias,
                                                  float* __restrict__ out, int n) {
    const int wv = threadIdx.x >> 6;
    const int lane = threadIdx.x & 63;
    const int grp = lane >> 4;
    const int fl = lane & 15;
    const int i = blockIdx.x * 4 + wv;
    if (i >= n) return;
    const float di = dis[i];
    float4 acc = make_float4(0.f, 0.f, 0.f, 0.f);
    if (grp == 0) {   // self loop counted once
        const float4 v = *(const float4*)&xw[(long)i * 64 + fl * 4];
        acc.x = di * v.x; acc.y = di * v.y; acc.z = di * v.z; acc.w = di * v.w;
    }
    const int s = offs[i];
    const int e = offs[i + 1];
    for (int j = s + grp; j < e; j += 4) {
        const int rs = csr[j];
        const float w = dis[rs];
        const float4 v = *(const float4*)&xw[(long)rs * 64 + fl * 4];
        acc.x = fmaf(w, v.x, acc.x); acc.y = fmaf(w, v.y, acc.y);
        acc.z = fmaf(w, v.z, acc.z); acc.w = fmaf(w, v.w, acc.w);
    }
    acc.x += __shfl_xor(acc.x, 16); acc.y += __shfl_xor(acc.y, 16);
    acc.z += __shfl_xor(acc.z, 16); acc.w += __shfl_xor(acc.w, 16);
    acc.x += __shfl_xor(acc.x, 32); acc.y += __shfl_xor(acc.y, 32);
    acc.z += __shfl_xor(acc.z, 32); acc.w += __shfl_xor(acc.w, 32);
    if (grp == 0) {
        const float4 b = *(const float4*)&bias[fl * 4];
        float4 o;
        o.x = fmaf(acc.x, di, b.x); o.y = fmaf(acc.y, di, b.y);
        o.z = fmaf(acc.z, di, b.z); o.w = fmaf(acc.w, di, b.w);
        if (RELU) {
            o.x = fmaxf(o.x, 0.f); o.y = fmaxf(o.y, 0.f);
            o.z = fmaxf(o.z, 0.f); o.w = fmaxf(o.w, 0.f);
        }
        *(float4*)&out[(long)i * 64 + fl * 4] = o;
    }
}

// 16 lanes per label edge: float4 gathers of z[src], z[dst]; 4-step xor reduce.
__global__ __launch_bounds__(256) void decode_kernel(const float* __restrict__ z,
                                                     const int* __restrict__ src,
                                                     const int* __restrict__ dst,
                                                     float* __restrict__ out, int L) {
    const int t = blockIdx.x * 256 + threadIdx.x;
    const int e = t >> 4;
    const int fl = t & 15;
    if (e >= L) return;
    const int s = src[e];
    const int d = dst[e];
    const float4 a = *(const float4*)&z[(long)s * 64 + fl * 4];
    const float4 b = *(const float4*)&z[(long)d * 64 + fl * 4];
    float p = a.x * b.x + a.y * b.y + a.z * b.z + a.w * b.w;
    p += __shfl_xor(p, 8); p += __shfl_xor(p, 4);
    p += __shfl_xor(p, 2); p += __shfl_xor(p, 1);
    if (fl == 0) out[e] = p;
}

extern "C" void kernel_launch(void* const* d_in, const int* in_sizes, int n_in,
                              void* d_out, int out_size, void* d_ws, size_t ws_size,
                              hipStream_t stream) {
    const float* x   = (const float*)d_in[0];
    const int*   ei  = (const int*)d_in[1];
    const int*   eli = (const int*)d_in[2];
    const float* W1  = (const float*)d_in[3];
    const float* b1  = (const float*)d_in[4];
    const float* W2  = (const float*)d_in[5];
    const float* b2  = (const float*)d_in[6];
    float* out = (float*)d_out;

    const int N = in_sizes[0] / 256;   // 50000 nodes (IN_CH = 256)
    const int E = in_sizes[1] / 2;     // 800000 edges
    const int L = in_sizes[2] / 2;     // 200000 label edges
    const int* row = ei;
    const int* col = ei + E;
    const int* src = eli;
    const int* dst = eli + L;

    char* w = (char*)d_ws;
    float* xw  = (float*)w;  w += (size_t)N * 64 * 4;   // pre-agg features (both layers)
    float* h   = (float*)w;  w += (size_t)N * 64 * 4;   // layer-1 output
    float* z   = (float*)w;  w += (size_t)N * 64 * 4;   // layer-2 output
    int*   csr = (int*)w;    w += (size_t)E * 4;        // sources sorted by target
    int*   offs = (int*)w;   w += (size_t)(N + 1) * 4;  // CSR offsets (N+1)
    float* dis = (float*)w;  w += (size_t)N * 4;        // rsqrt(deg+1)
    // aliases (dead before their hosts are written):
    int*  hist = (int*)h;    // NBPAD*NC ints (1MB) — consumed before agg1 writes h
    int2* part = (int2*)z;   // E int2 (6.4MB)     — consumed before agg2 writes z

    const int CE = (E + NC - 1) / NC;
    const int nbk = (N + (1 << BSHIFT) - 1) >> BSHIFT;   // 196 buckets

    hist_kernel<<<NC, 256, 0, stream>>>(col, hist, E, CE);
    scan_hist_kernel<<<1, 256, 0, stream>>>(hist);
    reorder_kernel<<<NC, 256, 0, stream>>>(row, col, hist, part, E, CE);
    bucket_csr_kernel<<<nbk, 256, 0, stream>>>(part, hist, csr, offs, dis, N, E, nbk);

    gemm_tile<256><<<(N + 63) / 64, 256, 0, stream>>>(x, W1, xw, N);
    agg_kernel<true><<<(N + 3) / 4, 256, 0, stream>>>(xw, csr, offs, dis, b1, h, N);
    gemm_tile<64><<<(N + 63) / 64, 256, 0, stream>>>(h, W2, xw, N);
    agg_kernel<false><<<(N + 3) / 4, 256, 0, stream>>>(xw, csr, offs, dis, b2, z, N);
    decode_kernel<<<(L + 15) / 16, 256, 0, stream>>>(z, src, dst, out, L);
}

// Round 6
// 235.806 us; speedup vs baseline: 2.0460x; 1.1302x over previous
//
#include <hip/hip_runtime.h>
#include <hip/hip_bf16.h>

// ---------------------------------------------------------------------------
// GCN: h = relu(gcnconv(x,W1,b1)); z = gcnconv(h,W2,b2); out[e]=dot(z[s],z[d])
// CSR build = bucketed counting sort (hist -> 3-stage scan -> reorder ->
// bucket_csr): all random writes land in block-owned windows.
// GEMM epilogue pre-scales rows by dis (xs = dis*(X@W)), so aggregation is
// a pure unweighted gather-sum: acc = xs[i] + sum xs[csr[j]]; out = di*acc+b.
// Agg batches 64 edge indices per wave via LDS (coalesced load + ds_read
// broadcast — NOT __shfl: bpermute from lanes made inactive by the
// group-divergent tail is undefined and caused R5's 0.45 absmax failure).
// ---------------------------------------------------------------------------

constexpr int NC = 256;      // edge chunks (= hist/reorder grid)
constexpr int NBPAD = 256;   // padded bucket count (>= nbk)
constexpr int BSHIFT = 8;    // 256 nodes per bucket

__global__ __launch_bounds__(256) void hist_kernel(const int* __restrict__ col,
                                                   int* __restrict__ hist, int E, int CE) {
    __shared__ int hl[NBPAD];
    const int t = threadIdx.x, c = blockIdx.x;
    hl[t] = 0;
    __syncthreads();
    const int s = c * CE, e = min(E, s + CE);
    for (int i = s + t; i < e; i += 256) atomicAdd(&hl[col[i] >> BSHIFT], 1);
    __syncthreads();
    hist[t * NC + c] = hl[t];   // bucket-major
}

// Per-bucket row sum (256 blocks).
__global__ __launch_bounds__(256) void bsum_kernel(const int* __restrict__ hist,
                                                   int* __restrict__ bsums) {
    __shared__ int red[256];
    const int t = threadIdx.x, b = blockIdx.x;
    red[t] = hist[b * NC + t];
    __syncthreads();
    for (int off = 128; off > 0; off >>= 1) {
        if (t < off) red[t] += red[t + off];
        __syncthreads();
    }
    if (t == 0) bsums[b] = red[0];
}

// Exclusive scan of 256 bucket sums (1 block).
__global__ __launch_bounds__(256) void bscan_kernel(int* __restrict__ bsums) {
    __shared__ int sc[256];
    const int t = threadIdx.x;
    const int v = bsums[t];
    sc[t] = v;
    __syncthreads();
    for (int off = 1; off < 256; off <<= 1) {
        int u = (t >= off) ? sc[t - off] : 0;
        __syncthreads();
        sc[t] += u;
        __syncthreads();
    }
    bsums[t] = sc[t] - v;   // exclusive
}

// Per-bucket row exclusive scan + bucket base (256 blocks).
__global__ __launch_bounds__(256) void rowscan_kernel(int* __restrict__ hist,
                                                      const int* __restrict__ bsums) {
    __shared__ int sc[256];
    const int t = threadIdx.x, b = blockIdx.x;
    const int v = hist[b * NC + t];
    sc[t] = v;
    __syncthreads();
    for (int off = 1; off < 256; off <<= 1) {
        int u = (t >= off) ? sc[t - off] : 0;
        __syncthreads();
        sc[t] += u;
        __syncthreads();
    }
    hist[b * NC + t] = sc[t] - v + bsums[b];
}

// Scatter (row,col) pairs into per-(bucket,chunk) contiguous runs of part[].
__global__ __launch_bounds__(256) void reorder_kernel(const int* __restrict__ row,
                                                      const int* __restrict__ col,
                                                      const int* __restrict__ hist,
                                                      int2* __restrict__ part, int E, int CE) {
    __shared__ int cur[NBPAD];
    const int t = threadIdx.x, c = blockIdx.x;
    cur[t] = hist[t * NC + c];
    __syncthreads();
    const int s = c * CE, e = min(E, s + CE);
    for (int i = s + t; i < e; i += 256) {
        const int r = row[i], cl = col[i];
        const int p = atomicAdd(&cur[cl >> BSHIFT], 1);
        part[p] = make_int2(r, cl);
    }
}

// One block per bucket: LDS degree count -> LDS scan -> offs/dis -> scatter
// rows into the bucket's private csr window.
__global__ __launch_bounds__(256) void bucket_csr_kernel(const int2* __restrict__ part,
                                                         const int* __restrict__ hist,
                                                         int* __restrict__ csr,
                                                         int* __restrict__ offs,
                                                         float* __restrict__ dis,
                                                         int N, int E, int nbk) {
    __shared__ int cnt[256];
    __shared__ int sc[256];
    const int t = threadIdx.x, b = blockIdx.x;
    const int base = b << BSHIFT;
    const int bstart = hist[b * NC];
    const int bend = (b + 1 < NBPAD) ? hist[(b + 1) * NC] : E;
    const int m = bend - bstart;
    cnt[t] = 0;
    __syncthreads();
    for (int i = t; i < m; i += 256) atomicAdd(&cnt[part[bstart + i].y - base], 1);
    __syncthreads();
    const int v = cnt[t];
    sc[t] = v;
    __syncthreads();
    for (int off = 1; off < 256; off <<= 1) {
        int u = (t >= off) ? sc[t - off] : 0;
        __syncthreads();
        sc[t] += u;
        __syncthreads();
    }
    const int excl = sc[t] - v;
    const int node = base + t;
    if (node < N) {
        offs[node] = bstart + excl;
        dis[node] = rsqrtf((float)(v + 1));   // +1 = self loop
    }
    sc[t] = excl;          // repurpose as scatter cursor
    __syncthreads();
    for (int i = t; i < m; i += 256) {
        const int2 ec = part[bstart + i];
        const int p = atomicAdd(&sc[ec.y - base], 1);
        csr[bstart + p] = ec.x;
    }
    if (b == nbk - 1 && t == 0) offs[N] = E;
}

// Y[N,64] = rowscale[r] * (X[N,K] @ W[K,64]).
// Block = 256 thr = 16x16 grid; 4x4 register micro-tile; both operands in
// LDS (k-major); per k: 2 ds_read_b128 + 16 FMAs, no global loads in k-loop.
template <int K>
__global__ __launch_bounds__(256) void gemm_tile(const float* __restrict__ X,
                                                 const float* __restrict__ W,
                                                 const float* __restrict__ rowscale,
                                                 float* __restrict__ Y, int nrows) {
    __shared__ float sX[64 * 64];
    __shared__ float sW[64 * 64];
    const int tid = threadIdx.x;
    const int tx = tid & 15;         // col group
    const int ty = tid >> 4;         // row group
    const int rowbase = blockIdx.x * 64;

    float acc[16];
    #pragma unroll
    for (int i = 0; i < 16; ++i) acc[i] = 0.f;

    const int lr = tid & 63;         // loader row (0..63)
    const int lq = tid >> 6;         // loader k-quarter (16 k's each)
    int grow = rowbase + lr;
    if (grow >= nrows) grow = nrows - 1;   // clamp; stores are guarded
    const float* xrow = X + (long)grow * K;

    for (int kc = 0; kc < K; kc += 64) {
        if (kc) __syncthreads();
        #pragma unroll
        for (int i = 0; i < 4; ++i) {
            const int o = tid * 4 + i * 1024;
            *(float4*)&sW[o] = *(const float4*)&W[(long)kc * 64 + o];
        }
        #pragma unroll
        for (int t = 0; t < 4; ++t) {
            const int k = lq * 16 + t * 4;
            const float4 v = *(const float4*)&xrow[kc + k];
            sX[(k + 0) * 64 + lr] = v.x;
            sX[(k + 1) * 64 + lr] = v.y;
            sX[(k + 2) * 64 + lr] = v.z;
            sX[(k + 3) * 64 + lr] = v.w;
        }
        __syncthreads();
        #pragma unroll 4
        for (int k = 0; k < 64; ++k) {
            const float4 xv = *(const float4*)&sX[k * 64 + ty * 4];
            const float4 wv = *(const float4*)&sW[k * 64 + tx * 4];
            acc[0]  = fmaf(xv.x, wv.x, acc[0]);
            acc[1]  = fmaf(xv.x, wv.y, acc[1]);
            acc[2]  = fmaf(xv.x, wv.z, acc[2]);
            acc[3]  = fmaf(xv.x, wv.w, acc[3]);
            acc[4]  = fmaf(xv.y, wv.x, acc[4]);
            acc[5]  = fmaf(xv.y, wv.y, acc[5]);
            acc[6]  = fmaf(xv.y, wv.z, acc[6]);
            acc[7]  = fmaf(xv.y, wv.w, acc[7]);
            acc[8]  = fmaf(xv.z, wv.x, acc[8]);
            acc[9]  = fmaf(xv.z, wv.y, acc[9]);
            acc[10] = fmaf(xv.z, wv.z, acc[10]);
            acc[11] = fmaf(xv.z, wv.w, acc[11]);
            acc[12] = fmaf(xv.w, wv.x, acc[12]);
            acc[13] = fmaf(xv.w, wv.y, acc[13]);
            acc[14] = fmaf(xv.w, wv.z, acc[14]);
            acc[15] = fmaf(xv.w, wv.w, acc[15]);
        }
    }

    #pragma unroll
    for (int i = 0; i < 4; ++i) {
        const int orow = rowbase + ty * 4 + i;
        if (orow < nrows) {
            const float d = rowscale[orow];
            *(float4*)&Y[(long)orow * 64 + tx * 4] =
                make_float4(d * acc[i * 4 + 0], d * acc[i * 4 + 1],
                            d * acc[i * 4 + 2], d * acc[i * 4 + 3]);
        }
    }
}

// One wave per node, 4 groups of 16 lanes (lane fl owns feats fl*4..+3).
// Batch: 64 edge indices loaded coalesced by the wave into LDS (same-wave DS
// ordering; ds_read of a group-uniform address = broadcast, exec-mask safe);
// inner loop has ONLY the 256B row gather (2 in flight per group).
template <bool RELU>
__global__ __launch_bounds__(256) void agg_kernel(const float* __restrict__ xs,
                                                  const int* __restrict__ csr,
                                                  const int* __restrict__ offs,
                                                  const float* __restrict__ dis,
                                                  const float* __restrict__ bias,
                                                  float* __restrict__ out, int n) {
    __shared__ int sidx[4][64];
    const int wv = threadIdx.x >> 6;
    const int lane = threadIdx.x & 63;
    const int grp = lane >> 4;
    const int fl = lane & 15;
    const int i = blockIdx.x * 4 + wv;
    if (i >= n) return;
    float4 acc = make_float4(0.f, 0.f, 0.f, 0.f);
    if (grp == 0)    // self loop counted once (xs already = dis*xw)
        acc = *(const float4*)&xs[(long)i * 64 + fl * 4];
    const int s = offs[i];
    const int e = offs[i + 1];
    for (int jb = s; jb < e; jb += 64) {
        const int nb = min(64, e - jb);
        if (lane < nb) sidx[wv][lane] = csr[jb + lane];
        // same-wave DS ops are processed in order: reads below see the writes
        int u = grp;
        for (; u + 4 < nb; u += 8) {
            const int r0 = sidx[wv][u];
            const int r1 = sidx[wv][u + 4];
            const float4 v0 = *(const float4*)&xs[(long)r0 * 64 + fl * 4];
            const float4 v1 = *(const float4*)&xs[(long)r1 * 64 + fl * 4];
            acc.x += v0.x + v1.x; acc.y += v0.y + v1.y;
            acc.z += v0.z + v1.z; acc.w += v0.w + v1.w;
        }
        for (; u < nb; u += 4) {
            const int r0 = sidx[wv][u];
            const float4 v0 = *(const float4*)&xs[(long)r0 * 64 + fl * 4];
            acc.x += v0.x; acc.y += v0.y; acc.z += v0.z; acc.w += v0.w;
        }
    }
    acc.x += __shfl_xor(acc.x, 16); acc.y += __shfl_xor(acc.y, 16);
    acc.z += __shfl_xor(acc.z, 16); acc.w += __shfl_xor(acc.w, 16);
    acc.x += __shfl_xor(acc.x, 32); acc.y += __shfl_xor(acc.y, 32);
    acc.z += __shfl_xor(acc.z, 32); acc.w += __shfl_xor(acc.w, 32);
    if (grp == 0) {
        const float di = dis[i];
        const float4 b = *(const float4*)&bias[fl * 4];
        float4 o;
        o.x = fmaf(acc.x, di, b.x); o.y = fmaf(acc.y, di, b.y);
        o.z = fmaf(acc.z, di, b.z); o.w = fmaf(acc.w, di, b.w);
        if (RELU) {
            o.x = fmaxf(o.x, 0.f); o.y = fmaxf(o.y, 0.f);
            o.z = fmaxf(o.z, 0.f); o.w = fmaxf(o.w, 0.f);
        }
        *(float4*)&out[(long)i * 64 + fl * 4] = o;
    }
}

// 16 lanes per label edge: float4 gathers of z[src], z[dst]; 4-step xor reduce.
__global__ __launch_bounds__(256) void decode_kernel(const float* __restrict__ z,
                                                     const int* __restrict__ src,
                                                     const int* __restrict__ dst,
                                                     float* __restrict__ out, int L) {
    const int t = blockIdx.x * 256 + threadIdx.x;
    const int e = t >> 4;
    const int fl = t & 15;
    if (e >= L) return;
    const int s = src[e];
    const int d = dst[e];
    const float4 a = *(const float4*)&z[(long)s * 64 + fl * 4];
    const float4 b = *(const float4*)&z[(long)d * 64 + fl * 4];
    float p = a.x * b.x + a.y * b.y + a.z * b.z + a.w * b.w;
    p += __shfl_xor(p, 8); p += __shfl_xor(p, 4);
    p += __shfl_xor(p, 2); p += __shfl_xor(p, 1);
    if (fl == 0) out[e] = p;
}

extern "C" void kernel_launch(void* const* d_in, const int* in_sizes, int n_in,
                              void* d_out, int out_size, void* d_ws, size_t ws_size,
                              hipStream_t stream) {
    const float* x   = (const float*)d_in[0];
    const int*   ei  = (const int*)d_in[1];
    const int*   eli = (const int*)d_in[2];
    const float* W1  = (const float*)d_in[3];
    const float* b1  = (const float*)d_in[4];
    const float* W2  = (const float*)d_in[5];
    const float* b2  = (const float*)d_in[6];
    float* out = (float*)d_out;

    const int N = in_sizes[0] / 256;   // 50000 nodes (IN_CH = 256)
    const int E = in_sizes[1] / 2;     // 800000 edges
    const int L = in_sizes[2] / 2;     // 200000 label edges
    const int* row = ei;
    const int* col = ei + E;
    const int* src = eli;
    const int* dst = eli + L;

    char* w = (char*)d_ws;
    float* xs  = (float*)w;  w += (size_t)N * 64 * 4;   // dis-scaled pre-agg feats
    float* h   = (float*)w;  w += (size_t)N * 64 * 4;   // layer-1 output
    float* z   = (float*)w;  w += (size_t)N * 64 * 4;   // layer-2 output
    int*   csr = (int*)w;    w += (size_t)E * 4;        // sources sorted by target
    int*   offs = (int*)w;   w += (size_t)(N + 1) * 4;  // CSR offsets (N+1)
    float* dis = (float*)w;  w += (size_t)N * 4;        // rsqrt(deg+1)
    // aliases (dead before their hosts are written):
    int*  hist  = (int*)h;                  // 256KB — consumed before agg1 writes h
    int*  bsums = hist + NBPAD * NC;        // 1KB, right after hist (still in h)
    int2* part  = (int2*)z;                 // E int2 (6.4MB) — consumed before agg2 writes z

    const int CE = (E + NC - 1) / NC;
    const int nbk = (N + (1 << BSHIFT) - 1) >> BSHIFT;   // 196 buckets

    hist_kernel<<<NC, 256, 0, stream>>>(col, hist, E, CE);
    bsum_kernel<<<NBPAD, 256, 0, stream>>>(hist, bsums);
    bscan_kernel<<<1, 256, 0, stream>>>(bsums);
    rowscan_kernel<<<NBPAD, 256, 0, stream>>>(hist, bsums);
    reorder_kernel<<<NC, 256, 0, stream>>>(row, col, hist, part, E, CE);
    bucket_csr_kernel<<<nbk, 256, 0, stream>>>(part, hist, csr, offs, dis, N, E, nbk);

    gemm_tile<256><<<(N + 63) / 64, 256, 0, stream>>>(x, W1, dis, xs, N);
    agg_kernel<true><<<(N + 3) / 4, 256, 0, stream>>>(xs, csr, offs, dis, b1, h, N);
    gemm_tile<64><<<(N + 63) / 64, 256, 0, stream>>>(h, W2, dis, xs, N);
    agg_kernel<false><<<(N + 3) / 4, 256, 0, stream>>>(xs, csr, offs, dis, b2, z, N);
    decode_kernel<<<(L + 15) / 16, 256, 0, stream>>>(z, src, dst, out, L);
}

// Round 7
// 223.197 us; speedup vs baseline: 2.1616x; 1.0565x over previous
//
#include <hip/hip_runtime.h>
#include <hip/hip_bf16.h>

// ---------------------------------------------------------------------------
// GCN: h = relu(gcnconv(x,W1,b1)); z = gcnconv(h,W2,b2); out[e]=dot(z[s],z[d])
// CSR build = bucketed counting sort (hist -> 3-stage scan -> reorder ->
// bucket_csr): all random writes land in block-owned windows.
// GEMM epilogue pre-scales rows by dis and packs to BF16: the gathered
// feature tables (xs both layers, z for decode) are bf16 -> random-gather
// traffic halves (128B/row). All accumulation stays fp32. h (dense,
// coalesced) stays fp32.
// Agg batches 64 edge indices per wave via LDS (coalesced load + ds_read
// broadcast — NOT __shfl: bpermute from lanes made inactive by the
// group-divergent tail is undefined; caused R5's 0.45 absmax failure).
// ---------------------------------------------------------------------------

constexpr int NC = 256;      // edge chunks (= hist/reorder grid)
constexpr int NBPAD = 256;   // padded bucket count (>= nbk)
constexpr int BSHIFT = 8;    // 256 nodes per bucket

__device__ __forceinline__ unsigned short f2bf(float f) {   // RNE, no NaN care
    unsigned u = __float_as_uint(f);
    return (unsigned short)((u + 0x7FFF + ((u >> 16) & 1)) >> 16);
}
__device__ __forceinline__ float bf2f(unsigned short h) {
    return __uint_as_float(((unsigned)h) << 16);
}
__device__ __forceinline__ float4 bf4_to_f4(ushort4 u) {
    return make_float4(bf2f(u.x), bf2f(u.y), bf2f(u.z), bf2f(u.w));
}

__global__ __launch_bounds__(256) void hist_kernel(const int* __restrict__ col,
                                                   int* __restrict__ hist, int E, int CE) {
    __shared__ int hl[NBPAD];
    const int t = threadIdx.x, c = blockIdx.x;
    hl[t] = 0;
    __syncthreads();
    const int s = c * CE, e = min(E, s + CE);
    for (int i = s + t; i < e; i += 256) atomicAdd(&hl[col[i] >> BSHIFT], 1);
    __syncthreads();
    hist[t * NC + c] = hl[t];   // bucket-major
}

// Per-bucket row sum (256 blocks).
__global__ __launch_bounds__(256) void bsum_kernel(const int* __restrict__ hist,
                                                   int* __restrict__ bsums) {
    __shared__ int red[256];
    const int t = threadIdx.x, b = blockIdx.x;
    red[t] = hist[b * NC + t];
    __syncthreads();
    for (int off = 128; off > 0; off >>= 1) {
        if (t < off) red[t] += red[t + off];
        __syncthreads();
    }
    if (t == 0) bsums[b] = red[0];
}

// Exclusive scan of 256 bucket sums (1 block).
__global__ __launch_bounds__(256) void bscan_kernel(int* __restrict__ bsums) {
    __shared__ int sc[256];
    const int t = threadIdx.x;
    const int v = bsums[t];
    sc[t] = v;
    __syncthreads();
    for (int off = 1; off < 256; off <<= 1) {
        int u = (t >= off) ? sc[t - off] : 0;
        __syncthreads();
        sc[t] += u;
        __syncthreads();
    }
    bsums[t] = sc[t] - v;   // exclusive
}

// Per-bucket row exclusive scan + bucket base (256 blocks).
__global__ __launch_bounds__(256) void rowscan_kernel(int* __restrict__ hist,
                                                      const int* __restrict__ bsums) {
    __shared__ int sc[256];
    const int t = threadIdx.x, b = blockIdx.x;
    const int v = hist[b * NC + t];
    sc[t] = v;
    __syncthreads();
    for (int off = 1; off < 256; off <<= 1) {
        int u = (t >= off) ? sc[t - off] : 0;
        __syncthreads();
        sc[t] += u;
        __syncthreads();
    }
    hist[b * NC + t] = sc[t] - v + bsums[b];
}

// Scatter (row,col) pairs into per-(bucket,chunk) contiguous runs of part[].
__global__ __launch_bounds__(256) void reorder_kernel(const int* __restrict__ row,
                                                      const int* __restrict__ col,
                                                      const int* __restrict__ hist,
                                                      int2* __restrict__ part, int E, int CE) {
    __shared__ int cur[NBPAD];
    const int t = threadIdx.x, c = blockIdx.x;
    cur[t] = hist[t * NC + c];
    __syncthreads();
    const int s = c * CE, e = min(E, s + CE);
    for (int i = s + t; i < e; i += 256) {
        const int r = row[i], cl = col[i];
        const int p = atomicAdd(&cur[cl >> BSHIFT], 1);
        part[p] = make_int2(r, cl);
    }
}

// One block per bucket: LDS degree count -> LDS scan -> offs/dis -> scatter
// rows into the bucket's private csr window.
__global__ __launch_bounds__(256) void bucket_csr_kernel(const int2* __restrict__ part,
                                                         const int* __restrict__ hist,
                                                         int* __restrict__ csr,
                                                         int* __restrict__ offs,
                                                         float* __restrict__ dis,
                                                         int N, int E, int nbk) {
    __shared__ int cnt[256];
    __shared__ int sc[256];
    const int t = threadIdx.x, b = blockIdx.x;
    const int base = b << BSHIFT;
    const int bstart = hist[b * NC];
    const int bend = (b + 1 < NBPAD) ? hist[(b + 1) * NC] : E;
    const int m = bend - bstart;
    cnt[t] = 0;
    __syncthreads();
    for (int i = t; i < m; i += 256) atomicAdd(&cnt[part[bstart + i].y - base], 1);
    __syncthreads();
    const int v = cnt[t];
    sc[t] = v;
    __syncthreads();
    for (int off = 1; off < 256; off <<= 1) {
        int u = (t >= off) ? sc[t - off] : 0;
        __syncthreads();
        sc[t] += u;
        __syncthreads();
    }
    const int excl = sc[t] - v;
    const int node = base + t;
    if (node < N) {
        offs[node] = bstart + excl;
        dis[node] = rsqrtf((float)(v + 1));   // +1 = self loop
    }
    sc[t] = excl;          // repurpose as scatter cursor
    __syncthreads();
    for (int i = t; i < m; i += 256) {
        const int2 ec = part[bstart + i];
        const int p = atomicAdd(&sc[ec.y - base], 1);
        csr[bstart + p] = ec.x;
    }
    if (b == nbk - 1 && t == 0) offs[N] = E;
}

// Y[N,64] (bf16) = rowscale[r] * (X[N,K] @ W[K,64]).
// Block = 256 thr = 16x16 grid; 4x4 register micro-tile; both operands in
// LDS (k-major); per k: 2 ds_read_b128 + 16 FMAs, no global loads in k-loop.
template <int K>
__global__ __launch_bounds__(256) void gemm_tile(const float* __restrict__ X,
                                                 const float* __restrict__ W,
                                                 const float* __restrict__ rowscale,
                                                 unsigned short* __restrict__ Y, int nrows) {
    __shared__ float sX[64 * 64];
    __shared__ float sW[64 * 64];
    const int tid = threadIdx.x;
    const int tx = tid & 15;         // col group
    const int ty = tid >> 4;         // row group
    const int rowbase = blockIdx.x * 64;

    float acc[16];
    #pragma unroll
    for (int i = 0; i < 16; ++i) acc[i] = 0.f;

    const int lr = tid & 63;         // loader row (0..63)
    const int lq = tid >> 6;         // loader k-quarter (16 k's each)
    int grow = rowbase + lr;
    if (grow >= nrows) grow = nrows - 1;   // clamp; stores are guarded
    const float* xrow = X + (long)grow * K;

    for (int kc = 0; kc < K; kc += 64) {
        if (kc) __syncthreads();
        #pragma unroll
        for (int i = 0; i < 4; ++i) {
            const int o = tid * 4 + i * 1024;
            *(float4*)&sW[o] = *(const float4*)&W[(long)kc * 64 + o];
        }
        #pragma unroll
        for (int t = 0; t < 4; ++t) {
            const int k = lq * 16 + t * 4;
            const float4 v = *(const float4*)&xrow[kc + k];
            sX[(k + 0) * 64 + lr] = v.x;
            sX[(k + 1) * 64 + lr] = v.y;
            sX[(k + 2) * 64 + lr] = v.z;
            sX[(k + 3) * 64 + lr] = v.w;
        }
        __syncthreads();
        #pragma unroll 4
        for (int k = 0; k < 64; ++k) {
            const float4 xv = *(const float4*)&sX[k * 64 + ty * 4];
            const float4 wv = *(const float4*)&sW[k * 64 + tx * 4];
            acc[0]  = fmaf(xv.x, wv.x, acc[0]);
            acc[1]  = fmaf(xv.x, wv.y, acc[1]);
            acc[2]  = fmaf(xv.x, wv.z, acc[2]);
            acc[3]  = fmaf(xv.x, wv.w, acc[3]);
            acc[4]  = fmaf(xv.y, wv.x, acc[4]);
            acc[5]  = fmaf(xv.y, wv.y, acc[5]);
            acc[6]  = fmaf(xv.y, wv.z, acc[6]);
            acc[7]  = fmaf(xv.y, wv.w, acc[7]);
            acc[8]  = fmaf(xv.z, wv.x, acc[8]);
            acc[9]  = fmaf(xv.z, wv.y, acc[9]);
            acc[10] = fmaf(xv.z, wv.z, acc[10]);
            acc[11] = fmaf(xv.z, wv.w, acc[11]);
            acc[12] = fmaf(xv.w, wv.x, acc[12]);
            acc[13] = fmaf(xv.w, wv.y, acc[13]);
            acc[14] = fmaf(xv.w, wv.z, acc[14]);
            acc[15] = fmaf(xv.w, wv.w, acc[15]);
        }
    }

    #pragma unroll
    for (int i = 0; i < 4; ++i) {
        const int orow = rowbase + ty * 4 + i;
        if (orow < nrows) {
            const float d = rowscale[orow];
            ushort4 ov;
            ov.x = f2bf(d * acc[i * 4 + 0]);
            ov.y = f2bf(d * acc[i * 4 + 1]);
            ov.z = f2bf(d * acc[i * 4 + 2]);
            ov.w = f2bf(d * acc[i * 4 + 3]);
            *(ushort4*)&Y[(long)orow * 64 + tx * 4] = ov;
        }
    }
}

// One wave per node, 4 groups of 16 lanes (lane fl owns feats fl*4..+3).
// xs is bf16 (128B/row). Batch: 64 edge indices loaded coalesced into LDS;
// inner loop has ONLY the 128B row gather (2 in flight per group).
// OUT_BF16: agg1 -> fp32 h (dense, feeds gemm2); agg2 -> bf16 z (gathered).
template <bool RELU, bool OUT_BF16>
__global__ __launch_bounds__(256) void agg_kernel(const unsigned short* __restrict__ xs,
                                                  const int* __restrict__ csr,
                                                  const int* __restrict__ offs,
                                                  const float* __restrict__ dis,
                                                  const float* __restrict__ bias,
                                                  void* __restrict__ out, int n) {
    __shared__ int sidx[4][64];
    const int wv = threadIdx.x >> 6;
    const int lane = threadIdx.x & 63;
    const int grp = lane >> 4;
    const int fl = lane & 15;
    const int i = blockIdx.x * 4 + wv;
    if (i >= n) return;
    float4 acc = make_float4(0.f, 0.f, 0.f, 0.f);
    if (grp == 0)    // self loop counted once (xs already = dis*xw)
        acc = bf4_to_f4(*(const ushort4*)&xs[(long)i * 64 + fl * 4]);
    const int s = offs[i];
    const int e = offs[i + 1];
    for (int jb = s; jb < e; jb += 64) {
        const int nb = min(64, e - jb);
        if (lane < nb) sidx[wv][lane] = csr[jb + lane];
        // same-wave DS ops are processed in order: reads below see the writes
        int u = grp;
        for (; u + 4 < nb; u += 8) {
            const int r0 = sidx[wv][u];
            const int r1 = sidx[wv][u + 4];
            const float4 v0 = bf4_to_f4(*(const ushort4*)&xs[(long)r0 * 64 + fl * 4]);
            const float4 v1 = bf4_to_f4(*(const ushort4*)&xs[(long)r1 * 64 + fl * 4]);
            acc.x += v0.x + v1.x; acc.y += v0.y + v1.y;
            acc.z += v0.z + v1.z; acc.w += v0.w + v1.w;
        }
        for (; u < nb; u += 4) {
            const int r0 = sidx[wv][u];
            const float4 v0 = bf4_to_f4(*(const ushort4*)&xs[(long)r0 * 64 + fl * 4]);
            acc.x += v0.x; acc.y += v0.y; acc.z += v0.z; acc.w += v0.w;
        }
    }
    acc.x += __shfl_xor(acc.x, 16); acc.y += __shfl_xor(acc.y, 16);
    acc.z += __shfl_xor(acc.z, 16); acc.w += __shfl_xor(acc.w, 16);
    acc.x += __shfl_xor(acc.x, 32); acc.y += __shfl_xor(acc.y, 32);
    acc.z += __shfl_xor(acc.z, 32); acc.w += __shfl_xor(acc.w, 32);
    if (grp == 0) {
        const float di = dis[i];
        const float4 b = *(const float4*)&bias[fl * 4];
        float4 o;
        o.x = fmaf(acc.x, di, b.x); o.y = fmaf(acc.y, di, b.y);
        o.z = fmaf(acc.z, di, b.z); o.w = fmaf(acc.w, di, b.w);
        if (RELU) {
            o.x = fmaxf(o.x, 0.f); o.y = fmaxf(o.y, 0.f);
            o.z = fmaxf(o.z, 0.f); o.w = fmaxf(o.w, 0.f);
        }
        if (OUT_BF16) {
            ushort4 ov;
            ov.x = f2bf(o.x); ov.y = f2bf(o.y); ov.z = f2bf(o.z); ov.w = f2bf(o.w);
            *(ushort4*)&((unsigned short*)out)[(long)i * 64 + fl * 4] = ov;
        } else {
            *(float4*)&((float*)out)[(long)i * 64 + fl * 4] = o;
        }
    }
}

// 16 lanes per label edge: bf16 gathers of z[src], z[dst]; 4-step xor reduce.
__global__ __launch_bounds__(256) void decode_kernel(const unsigned short* __restrict__ z,
                                                     const int* __restrict__ src,
                                                     const int* __restrict__ dst,
                                                     float* __restrict__ out, int L) {
    const int t = blockIdx.x * 256 + threadIdx.x;
    const int e = t >> 4;
    const int fl = t & 15;
    if (e >= L) return;
    const int s = src[e];
    const int d = dst[e];
    const float4 a = bf4_to_f4(*(const ushort4*)&z[(long)s * 64 + fl * 4]);
    const float4 b = bf4_to_f4(*(const ushort4*)&z[(long)d * 64 + fl * 4]);
    float p = a.x * b.x + a.y * b.y + a.z * b.z + a.w * b.w;
    p += __shfl_xor(p, 8); p += __shfl_xor(p, 4);
    p += __shfl_xor(p, 2); p += __shfl_xor(p, 1);
    if (fl == 0) out[e] = p;
}

extern "C" void kernel_launch(void* const* d_in, const int* in_sizes, int n_in,
                              void* d_out, int out_size, void* d_ws, size_t ws_size,
                              hipStream_t stream) {
    const float* x   = (const float*)d_in[0];
    const int*   ei  = (const int*)d_in[1];
    const int*   eli = (const int*)d_in[2];
    const float* W1  = (const float*)d_in[3];
    const float* b1  = (const float*)d_in[4];
    const float* W2  = (const float*)d_in[5];
    const float* b2  = (const float*)d_in[6];
    float* out = (float*)d_out;

    const int N = in_sizes[0] / 256;   // 50000 nodes (IN_CH = 256)
    const int E = in_sizes[1] / 2;     // 800000 edges
    const int L = in_sizes[2] / 2;     // 200000 label edges
    const int* row = ei;
    const int* col = ei + E;
    const int* src = eli;
    const int* dst = eli + L;

    char* w = (char*)d_ws;
    unsigned short* xs = (unsigned short*)w;  w += (size_t)N * 64 * 2;  // bf16 pre-agg feats
    float* h   = (float*)w;  w += (size_t)N * 64 * 4;                   // layer-1 output (fp32)
    unsigned short* z = (unsigned short*)w;  w += (size_t)N * 64 * 2;   // bf16 layer-2 output
    int*   csr = (int*)w;    w += (size_t)E * 4;        // sources sorted by target
    int*   offs = (int*)w;   w += (size_t)(N + 1) * 4;  // CSR offsets (N+1)
    float* dis = (float*)w;  w += (size_t)N * 4;        // rsqrt(deg+1)
    int2*  part = (int2*)w;  w += (size_t)E * 8;        // reorder staging (int2 per edge)
    // alias (dead before h is written):
    int*  hist  = (int*)h;                  // 256KB — consumed before agg1 writes h
    int*  bsums = hist + NBPAD * NC;        // 1KB, right after hist (still in h)

    const int CE = (E + NC - 1) / NC;
    const int nbk = (N + (1 << BSHIFT) - 1) >> BSHIFT;   // 196 buckets

    hist_kernel<<<NC, 256, 0, stream>>>(col, hist, E, CE);
    bsum_kernel<<<NBPAD, 256, 0, stream>>>(hist, bsums);
    bscan_kernel<<<1, 256, 0, stream>>>(bsums);
    rowscan_kernel<<<NBPAD, 256, 0, stream>>>(hist, bsums);
    reorder_kernel<<<NC, 256, 0, stream>>>(row, col, hist, part, E, CE);
    bucket_csr_kernel<<<nbk, 256, 0, stream>>>(part, hist, csr, offs, dis, N, E, nbk);

    gemm_tile<256><<<(N + 63) / 64, 256, 0, stream>>>(x, W1, dis, xs, N);
    agg_kernel<true, false><<<(N + 3) / 4, 256, 0, stream>>>(xs, csr, offs, dis, b1, h, N);
    gemm_tile<64><<<(N + 63) / 64, 256, 0, stream>>>(h, W2, dis, xs, N);
    agg_kernel<false, true><<<(N + 3) / 4, 256, 0, stream>>>(xs, csr, offs, dis, b2, z, N);
    decode_kernel<<<(L + 15) / 16, 256, 0, stream>>>(z, src, dst, out, L);
}